// Round 1
// baseline (73.642 us; speedup 1.0000x reference)
//
#include <hip/hip_runtime.h>

#define HOURS 24
#define NB 32
#define MM 128
#define LL 128
#define EE 128

// ws layout (floats)
#define WS_SUMS 0
#define WS_Q 16
#define WS_K (WS_Q + NB*MM*EE)
#define WS_V (WS_K + NB*MM*EE)
#define WS_SA (WS_V + NB*MM*EE)

// ---------------- Kernel P: 8 scalar row-sums of the 2x128 interval tables ----------
__global__ void k_sums(const float* __restrict__ sl, const float* __restrict__ su,
                       const float* __restrict__ tl, const float* __restrict__ tu,
                       float* __restrict__ ws) {
    int lane = threadIdx.x;  // 64 threads
    const float* tbls[4] = {sl, su, tl, tu};
    for (int c = 0; c < 8; ++c) {
        const float* t = tbls[c >> 1];
        int row = c & 1;
        float v = t[row * EE + lane] + t[row * EE + lane + 64];
        for (int off = 32; off >= 1; off >>= 1) v += __shfl_xor(v, off, 64);
        if (lane == 0) ws[WS_SUMS + c] = v;
    }
}

// ---------------- Kernel B: joint = gather-sum; q/k/v = joint @ W^T ----------------
__global__ __launch_bounds__(256) void k_qkv(
    const int* __restrict__ time_seq, const int* __restrict__ full_seq,
    const int* __restrict__ user,
    const float* __restrict__ emb_t, const float* __restrict__ emb_u,
    const float* __restrict__ emb_loc,
    const float* __restrict__ Wq, const float* __restrict__ Wk, const float* __restrict__ Wv,
    float* __restrict__ qout, float* __restrict__ kout, float* __restrict__ vout)
{
    __shared__ float j_lds[64][129];
    __shared__ float w_lds[128][129];
    int b = blockIdx.y;
    int which = blockIdx.x >> 1;
    int half = blockIdx.x & 1;
    int m0 = half * 64;
    const float* W = (which == 0) ? Wq : (which == 1) ? Wk : Wv;
    float* outp = (which == 0) ? qout : (which == 1) ? kout : vout;
    int tid = threadIdx.x;
    int uid = user[b];

    for (int i = tid; i < 128 * 128; i += 256) {
        int r = i >> 7, c = i & 127;
        w_lds[r][c] = W[i];
    }
    for (int i = tid; i < 64 * 128; i += 256) {
        int mm = i >> 7, e = i & 127;
        int m = m0 + mm;
        int t = time_seq[b * MM + m];
        int tim = (t - 1) % HOURS + 1;
        int locid = full_seq[b * MM + m];
        j_lds[mm][e] = emb_t[tim * EE + e] + emb_loc[locid * EE + e] + emb_u[uid * EE + e];
    }
    __syncthreads();

    int mg = tid >> 4;   // 0..15 -> 4 rows each
    int eg = tid & 15;   // 0..15 -> 8 cols each
    float acc[4][8];
#pragma unroll
    for (int a = 0; a < 4; ++a)
#pragma unroll
        for (int c = 0; c < 8; ++c) acc[a][c] = 0.f;

    for (int f = 0; f < 128; ++f) {
        float jv[4], wv[8];
#pragma unroll
        for (int a = 0; a < 4; ++a) jv[a] = j_lds[mg * 4 + a][f];
#pragma unroll
        for (int c = 0; c < 8; ++c) wv[c] = w_lds[eg * 8 + c][f];
#pragma unroll
        for (int a = 0; a < 4; ++a)
#pragma unroll
            for (int c = 0; c < 8; ++c) acc[a][c] += jv[a] * wv[c];
    }
#pragma unroll
    for (int a = 0; a < 4; ++a)
#pragma unroll
        for (int c = 0; c < 8; ++c)
            outp[(b * MM + m0 + mg * 4 + a) * EE + eg * 8 + c] = acc[a][c];
}

// ---------------- Kernel C: logits = qk^T + delta; softmax; *mask; @V -------------
__global__ __launch_bounds__(256) void k_attn(
    const float* __restrict__ q, const float* __restrict__ k, const float* __restrict__ v,
    const float* __restrict__ mat1, const int* __restrict__ traj_len,
    const float* __restrict__ sums, float* __restrict__ sa)
{
    __shared__ float k_lds[128][129];
    __shared__ float v_lds[128][129];
    __shared__ float q_lds[4][4][128];
    __shared__ float attw[4][4][128];
    int b = blockIdx.y;
    int chunk = blockIdx.x;   // 0..7, 16 rows per chunk
    int tid = threadIdx.x;
    int w = tid >> 6, lane = tid & 63;
    int tl = traj_len[b];

    for (int i = tid; i < 128 * 128; i += 256) {
        int r = i >> 7, c = i & 127;
        k_lds[r][c] = k[(b * MM + r) * EE + c];
        v_lds[r][c] = v[(b * MM + r) * EE + c];
    }
    int i0 = chunk * 16 + w * 4;
#pragma unroll
    for (int r = 0; r < 4; ++r) {
        q_lds[w][r][lane]      = q[(b * MM + i0 + r) * EE + lane];
        q_lds[w][r][lane + 64] = q[(b * MM + i0 + r) * EE + lane + 64];
    }
    float ssl[2] = {sums[0], sums[1]};
    float ssu[2] = {sums[2], sums[3]};
    float stl[2] = {sums[4], sums[5]};
    float stu[2] = {sums[6], sums[7]};
    float c0[2], c1[2], c2[2];
#pragma unroll
    for (int t = 0; t < 2; ++t) {
        c0[t] = ssl[t] + stl[t];
        c1[t] = (ssu[t] - ssl[t]) * 0.01f;
        c2[t] = (stu[t] - stl[t]) * 0.01f;
    }
    __syncthreads();

    // dot phase: 4 rows per wave, lane covers j=lane and j=lane+64
    float acc[4][2] = {{0.f,0.f},{0.f,0.f},{0.f,0.f},{0.f,0.f}};
    for (int e = 0; e < 128; ++e) {
        float k0 = k_lds[lane][e], k1 = k_lds[lane + 64][e];
#pragma unroll
        for (int r = 0; r < 4; ++r) {
            float qv = q_lds[w][r][e];
            acc[r][0] += qv * k0;
            acc[r][1] += qv * k1;
        }
    }
    // softmax per row (over all 128 j, then multiplied by mask — reference semantics)
#pragma unroll
    for (int r = 0; r < 4; ++r) {
        int i = i0 + r;
        int vi = (i < tl) ? 1 : 0;
        float lg[2];
        int m01[2];
#pragma unroll
        for (int h = 0; h < 2; ++h) {
            int j = lane + 64 * h;
            m01[h] = vi & ((j < tl) ? 1 : 0);
            float2 d = *(const float2*)&mat1[(size_t)((b * MM + i) * MM + j) * 2];
            lg[h] = acc[r][h] + c0[m01[h]] + c1[m01[h]] * d.x + c2[m01[h]] * d.y;
        }
        float mx = fmaxf(lg[0], lg[1]);
        for (int off = 32; off >= 1; off >>= 1) mx = fmaxf(mx, __shfl_xor(mx, off, 64));
        float e0 = __expf(lg[0] - mx), e1 = __expf(lg[1] - mx);
        float s = e0 + e1;
        for (int off = 32; off >= 1; off >>= 1) s += __shfl_xor(s, off, 64);
        float inv = 1.0f / s;
        attw[w][r][lane]      = e0 * inv * (float)m01[0];
        attw[w][r][lane + 64] = e1 * inv * (float)m01[1];
    }
    // attn @ V: lane covers e=lane and e=lane+64
    float accv[4][2] = {{0.f,0.f},{0.f,0.f},{0.f,0.f},{0.f,0.f}};
    for (int j = 0; j < 128; ++j) {
        float v0 = v_lds[j][lane], v1 = v_lds[j][lane + 64];
#pragma unroll
        for (int r = 0; r < 4; ++r) {
            float a = attw[w][r][j];
            accv[r][0] += a * v0;
            accv[r][1] += a * v1;
        }
    }
#pragma unroll
    for (int r = 0; r < 4; ++r) {
        sa[(b * MM + i0 + r) * EE + lane]      = accv[r][0];
        sa[(b * MM + i0 + r) * EE + lane + 64] = accv[r][1];
    }
}

// ---------------- Kernel D: out[b,l] = sum_m (cand_l . sa_m) * D[b,m,l] ------------
__global__ __launch_bounds__(256) void k_final(
    const float* __restrict__ sa, const int* __restrict__ posneg,
    const float* __restrict__ emb_loc, const float* __restrict__ mat2,
    const float* __restrict__ vecp, const int* __restrict__ traj_len,
    const float* __restrict__ sums, float* __restrict__ outp)
{
    __shared__ float sa_lds[128][129];
    __shared__ float cand[32][129];
    __shared__ float m2_lds[128][33];
    __shared__ float tms[128];
    __shared__ float bsv[128];
    int b = blockIdx.y;
    int l0 = blockIdx.x * 32;
    int tid = threadIdx.x;
    int w = tid >> 6, lane = tid & 63;
    int tl = traj_len[b];

    for (int i = tid; i < 128 * 128; i += 256) {
        int r = i >> 7, c = i & 127;
        sa_lds[r][c] = sa[(b * MM + r) * EE + c];
    }
    for (int i = tid; i < 32 * 128; i += 256) {
        int l = i >> 7, e = i & 127;
        int idx = posneg[b * LL + l0 + l];
        cand[l][e] = emb_loc[idx * EE + e];
    }
    for (int i = tid; i < 128 * 32; i += 256) {
        int m = i >> 5, c = i & 31;
        m2_lds[m][c] = mat2[(size_t)(b * MM + m) * LL + l0 + c];
    }
    if (tid < 128) {
        int m = tid;
        int vv = (m < tl) ? 1 : 0;
        float v_ssl = sums[0 + vv], v_ssu = sums[2 + vv];
        float v_stl = sums[4 + vv], v_stu = sums[6 + vv];
        tms[m] = v_ssl + v_stl + (v_stu - v_stl) * 0.01f * vecp[b * MM + m];
        bsv[m] = (v_ssu - v_ssl) * 0.01f;
    }
    __syncthreads();

    int jj0 = lane, jj1 = lane + 64;
    float g[8][2];
#pragma unroll
    for (int qq = 0; qq < 8; ++qq) { g[qq][0] = 0.f; g[qq][1] = 0.f; }
    for (int e = 0; e < 128; ++e) {
        float s0 = sa_lds[jj0][e], s1 = sa_lds[jj1][e];
#pragma unroll
        for (int qq = 0; qq < 8; ++qq) {
            float cv = cand[w * 8 + qq][e];
            g[qq][0] += cv * s0;
            g[qq][1] += cv * s1;
        }
    }
    float t0 = tms[jj0], t1 = tms[jj1], b0 = bsv[jj0], b1 = bsv[jj1];
#pragma unroll
    for (int qq = 0; qq < 8; ++qq) {
        int l = w * 8 + qq;
        float val = g[qq][0] * (t0 + b0 * m2_lds[jj0][l])
                  + g[qq][1] * (t1 + b1 * m2_lds[jj1][l]);
        for (int off = 32; off >= 1; off >>= 1) val += __shfl_xor(val, off, 64);
        if (lane == 0) outp[b * LL + l0 + l] = val;
    }
}

extern "C" void kernel_launch(void* const* d_in, const int* in_sizes, int n_in,
                              void* d_out, int out_size, void* d_ws, size_t ws_size,
                              hipStream_t stream) {
    const int* full_seq = (const int*)d_in[0];
    const int* time_seq = (const int*)d_in[1];
    const int* user     = (const int*)d_in[2];
    const int* posneg   = (const int*)d_in[3];
    const int* traj_len = (const int*)d_in[4];
    const float* mat1   = (const float*)d_in[5];
    const float* mat2   = (const float*)d_in[6];
    const float* vec    = (const float*)d_in[7];
    const float* emb_t  = (const float*)d_in[8];
    const float* emb_u  = (const float*)d_in[9];
    const float* emb_loc= (const float*)d_in[10];
    const float* emb_sl = (const float*)d_in[11];
    const float* emb_su = (const float*)d_in[12];
    const float* emb_tl = (const float*)d_in[13];
    const float* emb_tu = (const float*)d_in[14];
    const float* Wq     = (const float*)d_in[15];
    const float* Wk     = (const float*)d_in[16];
    const float* Wv     = (const float*)d_in[17];

    float* ws = (float*)d_ws;
    float* qbuf = ws + WS_Q;
    float* kbuf = ws + WS_K;
    float* vbuf = ws + WS_V;
    float* sabuf = ws + WS_SA;

    k_sums<<<1, 64, 0, stream>>>(emb_sl, emb_su, emb_tl, emb_tu, ws);
    k_qkv<<<dim3(6, 32), 256, 0, stream>>>(time_seq, full_seq, user,
                                           emb_t, emb_u, emb_loc,
                                           Wq, Wk, Wv, qbuf, kbuf, vbuf);
    k_attn<<<dim3(8, 32), 256, 0, stream>>>(qbuf, kbuf, vbuf, mat1, traj_len,
                                            ws + WS_SUMS, sabuf);
    k_final<<<dim3(4, 32), 256, 0, stream>>>(sabuf, posneg, emb_loc, mat2, vec,
                                             traj_len, ws + WS_SUMS, (float*)d_out);
}

// Round 2
// 24.175 us; speedup vs baseline: 3.0462x; 3.0462x over previous
//
#include <hip/hip_runtime.h>
#include <hip/hip_bf16.h>

#define HOURS 24
#define NB 32
#define MM 128
#define EE 128

typedef short bf16x8 __attribute__((ext_vector_type(8)));
typedef float f32x4 __attribute__((ext_vector_type(4)));

__device__ __forceinline__ unsigned short f2bfu(float f) {
    __hip_bfloat16 h = __float2bfloat16(f);
    return __builtin_bit_cast(unsigned short, h);
}
__device__ __forceinline__ unsigned int pack2(float a, float b) {
    return (unsigned int)f2bfu(a) | ((unsigned int)f2bfu(b) << 16);
}
// swizzled short-index of the 8-elem (16B) unit `unit` in row `row` of a [*][128] bf16 tile
__device__ __forceinline__ int swz8(int row, int unit) {
    return row * 128 + (((unit ^ (row & 7)) & 15) << 3);
}

// ---------------- Kernel 1: joint gather + Q/K/V via MFMA ----------------
// which<2: D = W (.) J^T  -> D[n][m], store q/k[m][n] (pack-4 contiguous)
// which=2: D = J (.) Wv^T -> D[m][n], store vt[n][m]  (pack-4 contiguous)
__global__ __launch_bounds__(256) void k_qkv(
    const int* __restrict__ time_seq, const int* __restrict__ full_seq,
    const int* __restrict__ user,
    const float* __restrict__ emb_t, const float* __restrict__ emb_u,
    const float* __restrict__ emb_loc,
    const float* __restrict__ Wq, const float* __restrict__ Wk, const float* __restrict__ Wv,
    short* __restrict__ qws, short* __restrict__ kws, short* __restrict__ vtws)
{
    __shared__ alignas(16) short Wl[128 * 128];
    __shared__ alignas(16) short Jl[64 * 128];
    int b = blockIdx.y;
    int which = blockIdx.x >> 1;
    int half = blockIdx.x & 1;
    int m0 = half * 64;
    int tid = threadIdx.x;
    const float* W = (which == 0) ? Wq : (which == 1) ? Wk : Wv;

    // stage W (f32 -> bf16, swizzled)
    const float4* W4 = (const float4*)W;
#pragma unroll
    for (int it = 0; it < 16; ++it) {
        int i4 = it * 256 + tid;          // 4096 float4
        float4 v = W4[i4];
        int n = i4 >> 5;
        int e = (i4 & 31) << 2;
        uint2 pk;
        pk.x = pack2(v.x, v.y);
        pk.y = pack2(v.z, v.w);
        *(uint2*)&Wl[swz8(n, e >> 3) + (e & 7)] = pk;
    }
    // stage joint-half (gather-sum, f32 -> bf16, swizzled)
    int uid = user[b];
    const float4* Eu4 = (const float4*)(emb_u + (size_t)uid * 128);
#pragma unroll
    for (int it = 0; it < 8; ++it) {
        int i4 = it * 256 + tid;          // 2048 float4
        int mm = i4 >> 5;
        int e = (i4 & 31) << 2;
        int m = m0 + mm;
        int t = time_seq[b * MM + m];
        int tim = (t - 1) % HOURS + 1;
        int loc = full_seq[b * MM + m];
        float4 a = ((const float4*)(emb_t + (size_t)tim * 128))[e >> 2];
        float4 c = ((const float4*)(emb_loc + (size_t)loc * 128))[e >> 2];
        float4 u = Eu4[e >> 2];
        uint2 pk;
        pk.x = pack2(a.x + c.x + u.x, a.y + c.y + u.y);
        pk.y = pack2(a.z + c.z + u.z, a.w + c.w + u.w);
        *(uint2*)&Jl[swz8(mm, e >> 3) + (e & 7)] = pk;
    }
    __syncthreads();

    int l = tid & 63, w = tid >> 6;
    int lr = l & 15, lg = l >> 4;

    if (which < 2) {
        bf16x8 af[2][4];
#pragma unroll
        for (int nt = 0; nt < 2; ++nt) {
            int n = (2 * w + nt) * 16 + lr;
#pragma unroll
            for (int kf = 0; kf < 4; ++kf)
                af[nt][kf] = *(const bf16x8*)&Wl[swz8(n, kf * 4 + lg)];
        }
        f32x4 acc[2][4];
#pragma unroll
        for (int nt = 0; nt < 2; ++nt)
#pragma unroll
            for (int mt = 0; mt < 4; ++mt) acc[nt][mt] = (f32x4){0.f, 0.f, 0.f, 0.f};
#pragma unroll
        for (int mt = 0; mt < 4; ++mt) {
            int m = mt * 16 + lr;
            bf16x8 bf[4];
#pragma unroll
            for (int kf = 0; kf < 4; ++kf)
                bf[kf] = *(const bf16x8*)&Jl[swz8(m, kf * 4 + lg)];
#pragma unroll
            for (int nt = 0; nt < 2; ++nt)
#pragma unroll
                for (int kf = 0; kf < 4; ++kf)
                    acc[nt][mt] = __builtin_amdgcn_mfma_f32_16x16x32_bf16(af[nt][kf], bf[kf], acc[nt][mt], 0, 0, 0);
        }
        short* outp = (which == 0) ? qws : kws;
#pragma unroll
        for (int nt = 0; nt < 2; ++nt)
#pragma unroll
            for (int mt = 0; mt < 4; ++mt) {
                int mg = m0 + mt * 16 + lr;
                int n0 = (2 * w + nt) * 16 + lg * 4;
                f32x4 a = acc[nt][mt];
                uint2 pk;
                pk.x = pack2(a[0], a[1]);
                pk.y = pack2(a[2], a[3]);
                *(uint2*)&outp[(size_t)(b * MM + mg) * EE + n0] = pk;
            }
    } else {
        bf16x8 bfr[2][4];
#pragma unroll
        for (int nt = 0; nt < 2; ++nt) {
            int n = (2 * w + nt) * 16 + lr;
#pragma unroll
            for (int kf = 0; kf < 4; ++kf)
                bfr[nt][kf] = *(const bf16x8*)&Wl[swz8(n, kf * 4 + lg)];
        }
        f32x4 acc[4][2];
#pragma unroll
        for (int mt = 0; mt < 4; ++mt)
#pragma unroll
            for (int nt = 0; nt < 2; ++nt) acc[mt][nt] = (f32x4){0.f, 0.f, 0.f, 0.f};
#pragma unroll
        for (int mt = 0; mt < 4; ++mt) {
            int m = mt * 16 + lr;
            bf16x8 af[4];
#pragma unroll
            for (int kf = 0; kf < 4; ++kf)
                af[kf] = *(const bf16x8*)&Jl[swz8(m, kf * 4 + lg)];
#pragma unroll
            for (int nt = 0; nt < 2; ++nt)
#pragma unroll
                for (int kf = 0; kf < 4; ++kf)
                    acc[mt][nt] = __builtin_amdgcn_mfma_f32_16x16x32_bf16(af[kf], bfr[nt][kf], acc[mt][nt], 0, 0, 0);
        }
#pragma unroll
        for (int mt = 0; mt < 4; ++mt)
#pragma unroll
            for (int nt = 0; nt < 2; ++nt) {
                int ng = (2 * w + nt) * 16 + lr;
                int mp = m0 + mt * 16 + lg * 4;
                f32x4 a = acc[mt][nt];
                uint2 pk;
                pk.x = pack2(a[0], a[1]);
                pk.y = pack2(a[2], a[3]);
                *(uint2*)&vtws[(size_t)(b * MM + ng) * MM + mp] = pk;
            }
    }
}

// ---------------- Kernel 2: attention (QK^T + delta, softmax, *mask, @V) ----------
__global__ __launch_bounds__(256) void k_attn(
    const short* __restrict__ qws, const short* __restrict__ kws,
    const short* __restrict__ vtws,
    const float* __restrict__ mat1, const int* __restrict__ traj_len,
    const float* __restrict__ esl, const float* __restrict__ esu,
    const float* __restrict__ etl, const float* __restrict__ etu,
    short* __restrict__ saws)
{
    __shared__ alignas(16) short Kl[128 * 128];
    __shared__ alignas(16) short VTl[128 * 128];
    __shared__ alignas(16) short Pl[16 * 128];
    __shared__ alignas(16) float Sl[16][132];
    __shared__ float coef[8];

    int b = blockIdx.y;
    int chunk = blockIdx.x;
    int i0 = chunk * 16;
    int tid = threadIdx.x;
    int l = tid & 63, w = tid >> 6;
    int lr = l & 15, lg = l >> 4;
    int tl = traj_len[b];

    // coefs: wave w computes table sums 2w, 2w+1 (row 0 of tables is zero by construction)
    {
        const float* tb[4] = {esl, esu, etl, etu};
#pragma unroll
        for (int s = 0; s < 2; ++s) {
            int c = 2 * w + s;
            const float* t = tb[c >> 1];
            float v = t[(c & 1) * 128 + l] + t[(c & 1) * 128 + 64 + l];
#pragma unroll
            for (int off = 32; off >= 1; off >>= 1) v += __shfl_xor(v, off, 64);
            if (l == 0) coef[c] = v;
        }
    }
    // stage K and VT (bf16, swizzled)
    const uint4* K4 = (const uint4*)(kws + (size_t)b * MM * EE);
    const uint4* VT4 = (const uint4*)(vtws + (size_t)b * MM * MM);
#pragma unroll
    for (int it = 0; it < 8; ++it) {
        int U = it * 256 + tid;          // 2048 16B-units
        int r = U >> 4, u = U & 15;
        *(uint4*)&Kl[swz8(r, u)] = K4[U];
    }
#pragma unroll
    for (int it = 0; it < 8; ++it) {
        int U = it * 256 + tid;
        int r = U >> 4, u = U & 15;
        *(uint4*)&VTl[swz8(r, u)] = VT4[U];
    }
    // Q A-frags direct from global
    bf16x8 qf[4];
#pragma unroll
    for (int kf = 0; kf < 4; ++kf)
        qf[kf] = *(const bf16x8*)&qws[(size_t)(b * MM + i0 + lr) * EE + kf * 32 + lg * 8];
    __syncthreads();

    // QK^T: wave w covers j-tiles {2w, 2w+1}
    f32x4 accs[2];
#pragma unroll
    for (int t2 = 0; t2 < 2; ++t2) accs[t2] = (f32x4){0.f, 0.f, 0.f, 0.f};
#pragma unroll
    for (int t2 = 0; t2 < 2; ++t2) {
        int j = (2 * w + t2) * 16 + lr;
#pragma unroll
        for (int kf = 0; kf < 4; ++kf) {
            bf16x8 bf = *(const bf16x8*)&Kl[swz8(j, kf * 4 + lg)];
            accs[t2] = __builtin_amdgcn_mfma_f32_16x16x32_bf16(qf[kf], bf, accs[t2], 0, 0, 0);
        }
    }
#pragma unroll
    for (int t2 = 0; t2 < 2; ++t2) {
        int jc = (2 * w + t2) * 16 + lr;
#pragma unroll
        for (int r = 0; r < 4; ++r) Sl[lg * 4 + r][jc] = accs[t2][r];
    }
    __syncthreads();

    // softmax: thread = (row r16, 8-col chunk u)
    {
        int r16 = tid >> 4, u = tid & 15;
        int j0 = u * 8;
        int i = i0 + r16;
        int mi = (i < tl) ? 1 : 0;
        float c0_1 = coef[1] + coef[5];
        float c1_1 = (coef[3] - coef[1]) * 0.01f;
        float c2_1 = (coef[7] - coef[5]) * 0.01f;
        float c0_0 = coef[0] + coef[4];
        float c1_0 = (coef[2] - coef[0]) * 0.01f;
        float c2_0 = (coef[6] - coef[4]) * 0.01f;
        float4 s01 = *(float4*)&Sl[r16][j0];
        float4 s23 = *(float4*)&Sl[r16][j0 + 4];
        float sv[8] = {s01.x, s01.y, s01.z, s01.w, s23.x, s23.y, s23.z, s23.w};
        const float4* m14 = (const float4*)(mat1 + (size_t)(b * MM + i) * MM * 2 + j0 * 2);
        float4 d0 = m14[0], d1 = m14[1], d2 = m14[2], d3 = m14[3];
        float ds[8] = {d0.x, d0.z, d1.x, d1.z, d2.x, d2.z, d3.x, d3.z};
        float dt[8] = {d0.y, d0.w, d1.y, d1.w, d2.y, d2.w, d3.y, d3.w};
        float lgv[8];
        int mk[8];
#pragma unroll
        for (int jj = 0; jj < 8; ++jj) {
            int j = j0 + jj;
            mk[jj] = mi & ((j < tl) ? 1 : 0);
            float cc0 = mk[jj] ? c0_1 : c0_0;
            float cc1 = mk[jj] ? c1_1 : c1_0;
            float cc2 = mk[jj] ? c2_1 : c2_0;
            lgv[jj] = sv[jj] + cc0 + cc1 * ds[jj] + cc2 * dt[jj];
        }
        float mx = lgv[0];
#pragma unroll
        for (int jj = 1; jj < 8; ++jj) mx = fmaxf(mx, lgv[jj]);
#pragma unroll
        for (int off = 8; off >= 1; off >>= 1) mx = fmaxf(mx, __shfl_xor(mx, off, 64));
        float ee[8], sum = 0.f;
#pragma unroll
        for (int jj = 0; jj < 8; ++jj) { ee[jj] = __expf(lgv[jj] - mx); sum += ee[jj]; }
#pragma unroll
        for (int off = 8; off >= 1; off >>= 1) sum += __shfl_xor(sum, off, 64);
        float inv = 1.0f / sum;
        float p[8];
#pragma unroll
        for (int jj = 0; jj < 8; ++jj) p[jj] = ee[jj] * inv * (float)mk[jj];
        uint4 pk;
        pk.x = pack2(p[0], p[1]);
        pk.y = pack2(p[2], p[3]);
        pk.z = pack2(p[4], p[5]);
        pk.w = pack2(p[6], p[7]);
        *(uint4*)&Pl[swz8(r16, u)] = pk;
    }
    __syncthreads();

    // sa^T = VT (.) P^T : A = VT rows e, B cols i ; D[e][i] -> store sa[i][e] pack-4
    bf16x8 bp[4];
#pragma unroll
    for (int kf = 0; kf < 4; ++kf)
        bp[kf] = *(const bf16x8*)&Pl[swz8(lr, kf * 4 + lg)];
    f32x4 accv[2];
#pragma unroll
    for (int t2 = 0; t2 < 2; ++t2) accv[t2] = (f32x4){0.f, 0.f, 0.f, 0.f};
#pragma unroll
    for (int t2 = 0; t2 < 2; ++t2) {
        int e = (2 * w + t2) * 16 + lr;
#pragma unroll
        for (int kf = 0; kf < 4; ++kf) {
            bf16x8 af = *(const bf16x8*)&VTl[swz8(e, kf * 4 + lg)];
            accv[t2] = __builtin_amdgcn_mfma_f32_16x16x32_bf16(af, bp[kf], accv[t2], 0, 0, 0);
        }
    }
#pragma unroll
    for (int t2 = 0; t2 < 2; ++t2) {
        int ig = i0 + lr;
        int e0 = (2 * w + t2) * 16 + lg * 4;
        f32x4 a = accv[t2];
        uint2 pk;
        pk.x = pack2(a[0], a[1]);
        pk.y = pack2(a[2], a[3]);
        *(uint2*)&saws[(size_t)(b * MM + ig) * EE + e0] = pk;
    }
}

// ---------------- Kernel 3: G = cand (.) sa^T ; out[l] = sum_m G[l][m]*(tms[m]+bsv[m]*mat2[m][l])
__global__ __launch_bounds__(256) void k_final(
    const short* __restrict__ saws, const int* __restrict__ posneg,
    const float* __restrict__ emb_loc, const float* __restrict__ mat2,
    const float* __restrict__ vecg, const int* __restrict__ traj_len,
    const float* __restrict__ esl, const float* __restrict__ esu,
    const float* __restrict__ etl, const float* __restrict__ etu,
    float* __restrict__ outp)
{
    __shared__ alignas(16) short SAl[128 * 128];
    __shared__ alignas(16) short CAl[32 * 128];
    __shared__ alignas(16) float M2l[128 * 36];
    __shared__ float TMS[128];
    __shared__ float BSV[128];
    __shared__ float PART[2][32];
    __shared__ float coef[8];

    int b = blockIdx.y;
    int l0 = blockIdx.x * 32;
    int tid = threadIdx.x;
    int l = tid & 63, w = tid >> 6;
    int lr = l & 15, lg = l >> 4;
    int tl = traj_len[b];

    {
        const float* tb[4] = {esl, esu, etl, etu};
#pragma unroll
        for (int s = 0; s < 2; ++s) {
            int c = 2 * w + s;
            const float* t = tb[c >> 1];
            float v = t[(c & 1) * 128 + l] + t[(c & 1) * 128 + 64 + l];
#pragma unroll
            for (int off = 32; off >= 1; off >>= 1) v += __shfl_xor(v, off, 64);
            if (l == 0) coef[c] = v;
        }
    }
    // stage sa (bf16 swizzled)
    const uint4* SA4 = (const uint4*)(saws + (size_t)b * MM * EE);
#pragma unroll
    for (int it = 0; it < 8; ++it) {
        int U = it * 256 + tid;
        int r = U >> 4, u = U & 15;
        *(uint4*)&SAl[swz8(r, u)] = SA4[U];
    }
    // stage cand (gather f32 -> bf16 swizzled)
#pragma unroll
    for (int it = 0; it < 4; ++it) {
        int i4 = it * 256 + tid;          // 1024 float4
        int lrow = i4 >> 5;
        int e = (i4 & 31) << 2;
        int p = posneg[b * MM + l0 + lrow];
        float4 v = ((const float4*)(emb_loc + (size_t)p * 128))[e >> 2];
        uint2 pk;
        pk.x = pack2(v.x, v.y);
        pk.y = pack2(v.z, v.w);
        *(uint2*)&CAl[swz8(lrow, e >> 3) + (e & 7)] = pk;
    }
    // stage mat2 chunk [128 m][32 l] f32, padded stride 36
#pragma unroll
    for (int it = 0; it < 4; ++it) {
        int i4 = it * 256 + tid;          // 1024 float4
        int m = i4 >> 3;
        int c = (i4 & 7) << 2;
        float4 v = ((const float4*)(mat2 + (size_t)(b * MM + m) * MM + l0))[c >> 2];
        *(float4*)&M2l[m * 36 + c] = v;
    }
    __syncthreads();

    if (tid < 128) {
        int vv = (tid < tl) ? 1 : 0;
        float ssl = vv ? coef[1] : coef[0];
        float ssu = vv ? coef[3] : coef[2];
        float stl = vv ? coef[5] : coef[4];
        float stu = vv ? coef[7] : coef[6];
        TMS[tid] = ssl + stl + (stu - stl) * 0.01f * vecg[b * MM + tid];
        BSV[tid] = (ssu - ssl) * 0.01f;
    }

    // G tiles: wave (ltile = w&1, mhalf = w>>1), m-tiles mhalf*4 + 0..3
    int ltile = w & 1, mhalf = w >> 1;
    bf16x8 ca[4];
#pragma unroll
    for (int kf = 0; kf < 4; ++kf)
        ca[kf] = *(const bf16x8*)&CAl[swz8(ltile * 16 + lr, kf * 4 + lg)];
    f32x4 acc[4];
#pragma unroll
    for (int mt = 0; mt < 4; ++mt) acc[mt] = (f32x4){0.f, 0.f, 0.f, 0.f};
#pragma unroll
    for (int mt = 0; mt < 4; ++mt) {
        int m = (mhalf * 4 + mt) * 16 + lr;
#pragma unroll
        for (int kf = 0; kf < 4; ++kf) {
            bf16x8 bf = *(const bf16x8*)&SAl[swz8(m, kf * 4 + lg)];
            acc[mt] = __builtin_amdgcn_mfma_f32_16x16x32_bf16(ca[kf], bf, acc[mt], 0, 0, 0);
        }
    }
    __syncthreads();   // TMS/BSV ready for everyone

#pragma unroll
    for (int r = 0; r < 4; ++r) {
        int lrel = ltile * 16 + lg * 4 + r;
        float vs = 0.f;
#pragma unroll
        for (int mt = 0; mt < 4; ++mt) {
            int m = (mhalf * 4 + mt) * 16 + lr;
            vs += acc[mt][r] * (TMS[m] + BSV[m] * M2l[m * 36 + lrel]);
        }
#pragma unroll
        for (int off = 8; off >= 1; off >>= 1) vs += __shfl_xor(vs, off, 64);
        if (lr == 0) PART[mhalf][lrel] = vs;
    }
    __syncthreads();
    if (tid < 32) outp[b * MM + l0 + tid] = PART[0][tid] + PART[1][tid];
}

extern "C" void kernel_launch(void* const* d_in, const int* in_sizes, int n_in,
                              void* d_out, int out_size, void* d_ws, size_t ws_size,
                              hipStream_t stream) {
    const int* full_seq = (const int*)d_in[0];
    const int* time_seq = (const int*)d_in[1];
    const int* user     = (const int*)d_in[2];
    const int* posneg   = (const int*)d_in[3];
    const int* traj_len = (const int*)d_in[4];
    const float* mat1   = (const float*)d_in[5];
    const float* mat2   = (const float*)d_in[6];
    const float* vec    = (const float*)d_in[7];
    const float* emb_t  = (const float*)d_in[8];
    const float* emb_u  = (const float*)d_in[9];
    const float* emb_loc= (const float*)d_in[10];
    const float* emb_sl = (const float*)d_in[11];
    const float* emb_su = (const float*)d_in[12];
    const float* emb_tl = (const float*)d_in[13];
    const float* emb_tu = (const float*)d_in[14];
    const float* Wq     = (const float*)d_in[15];
    const float* Wk     = (const float*)d_in[16];
    const float* Wv     = (const float*)d_in[17];

    short* qws  = (short*)d_ws;
    short* kws  = qws + (size_t)NB * MM * EE;
    short* vtws = kws + (size_t)NB * MM * EE;
    short* saws = vtws + (size_t)NB * MM * EE;

    k_qkv<<<dim3(6, 32), 256, 0, stream>>>(time_seq, full_seq, user,
                                           emb_t, emb_u, emb_loc,
                                           Wq, Wk, Wv, qws, kws, vtws);
    k_attn<<<dim3(8, 32), 256, 0, stream>>>(qws, kws, vtws, mat1, traj_len,
                                            emb_sl, emb_su, emb_tl, emb_tu, saws);
    k_final<<<dim3(4, 32), 256, 0, stream>>>(saws, posneg, emb_loc, mat2, vec,
                                             traj_len, emb_sl, emb_su, emb_tl, emb_tu,
                                             (float*)d_out);
}